// Round 2
// baseline (497.293 us; speedup 1.0000x reference)
//
#include <hip/hip_runtime.h>
#include <hip/hip_bf16.h>

// Problem constants (from reference setup_inputs / NUM_DISPARITIES)
constexpr int B = 2, C = 32, H = 136, W = 240, D = 48;
constexpr int W4      = W / 4;        // 60 float4 per row
constexpr int PLANE   = H * W;        // 32640 elements per (b,c) plane
constexpr int PLANE4  = PLANE / 4;    // 8160 float4 per plane
constexpr int NPLANES = B * C * D;    // 3072 output planes
constexpr float CLAMP = 1000.0f;

// Native (clang ext_vector) 4-float — required by __builtin_nontemporal_store;
// HIP's float4 is a class type the builtin rejects.
typedef float v4f __attribute__((ext_vector_type(4)));

__device__ __forceinline__ float clampv(float x) {
    return fminf(CLAMP, fmaxf(-CLAMP, x));
}

// out[b,c,d,h,w] = clamp(left[b,c,h,w] * right[b,c,h,w-d], +-1000), 0 if w < d
// One block per output plane p = (b*C+c)*D + d. Threads grid-stride over the
// 8160 float4 slots of the plane. Output stores are aligned 16B, coalesced,
// non-temporal (write-once, never read back — don't pollute L2 caching the
// inputs). Inputs are ~8 MB each, served from L1/L2/L3 with D=48x reuse.
__global__ __launch_bounds__(256) void CostVolume_4939212390829_kernel(
        const float* __restrict__ left,
        const float* __restrict__ right,
        float* __restrict__ out) {
    const int p  = blockIdx.x;        // plane index = bc*D + d
    const int bc = p / D;
    const int d  = p % D;

    const float* __restrict__ lplane = left  + (size_t)bc * PLANE;
    const float* __restrict__ rplane = right + (size_t)bc * PLANE;
    float* __restrict__ oplane = out + (size_t)p * PLANE;

    for (int i = threadIdx.x; i < PLANE4; i += 256) {
        const int h = i / W4;
        const int w = (i - h * W4) * 4;
        const int row = h * W;

        const v4f l4 = *(const v4f*)(lplane + row + w);

        // gathered right values: src = w + j - d, zero when src < 0
        const float* __restrict__ rrow = rplane + row + (w - d);
        float r0 = (w + 0 >= d) ? rrow[0] : 0.0f;
        float r1 = (w + 1 >= d) ? rrow[1] : 0.0f;
        float r2 = (w + 2 >= d) ? rrow[2] : 0.0f;
        float r3 = (w + 3 >= d) ? rrow[3] : 0.0f;

        v4f o4;
        o4.x = clampv(l4.x * r0);
        o4.y = clampv(l4.y * r1);
        o4.z = clampv(l4.z * r2);
        o4.w = clampv(l4.w * r3);

        __builtin_nontemporal_store(o4, (v4f*)(oplane + i * 4));
    }
}

extern "C" void kernel_launch(void* const* d_in, const int* in_sizes, int n_in,
                              void* d_out, int out_size, void* d_ws, size_t ws_size,
                              hipStream_t stream) {
    const float* left  = (const float*)d_in[0];
    const float* right = (const float*)d_in[1];
    float* out = (float*)d_out;
    (void)in_sizes; (void)n_in; (void)out_size; (void)d_ws; (void)ws_size;

    CostVolume_4939212390829_kernel<<<NPLANES, 256, 0, stream>>>(left, right, out);
}